// Round 9
// baseline (522.467 us; speedup 1.0000x reference)
//
#include <hip/hip_runtime.h>
#include <hip/hip_bf16.h>

typedef __attribute__((ext_vector_type(4))) float fx4;
typedef __attribute__((ext_vector_type(8))) short bx8;
typedef __hip_bfloat16 bf16;

#define GLD16(dst, src)                                                        \
  __builtin_amdgcn_global_load_lds(                                            \
      (__attribute__((address_space(1))) void*)(src),                          \
      (__attribute__((address_space(3))) void*)(dst), 16, 0, 0)

__device__ inline float bf2f(short s_) {
  unsigned int u = ((unsigned int)(unsigned short)s_) << 16;
  float f;
  __builtin_memcpy(&f, &u, 4);
  return f;
}
__device__ inline short f2bf(float f) {
  __hip_bfloat16 h = __float2bfloat16(f);
  short r;
  __builtin_memcpy(&r, &h, 2);
  return r;
}

// ---------------------------------------------------------------- cast x->bf16
__global__ __launch_bounds__(256) void k_cast(const float* __restrict__ in,
                                              bf16* __restrict__ out, int n4) {
  int i = blockIdx.x * 256 + threadIdx.x;
  if (i >= n4) return;
  float4 v = reinterpret_cast<const float4*>(in)[i];
  bf16 t[4] = {__float2bfloat16(v.x), __float2bfloat16(v.y),
               __float2bfloat16(v.z), __float2bfloat16(v.w)};
  reinterpret_cast<ushort4*>(out)[i] = *reinterpret_cast<ushort4*>(t);
}

// ------------------------------------------- transpose-cast fp32 RxC -> bf16 CxR
__global__ void k_tcast(const float* __restrict__ in, bf16* __restrict__ out,
                        int R, int C) {
  __shared__ float tile[32][33];
  int c0 = blockIdx.x * 32, r0 = blockIdx.y * 32;
  int tx = threadIdx.x, ty = threadIdx.y;
#pragma unroll
  for (int j = 0; j < 4; ++j)
    tile[ty + j * 8][tx] = in[(size_t)(r0 + ty + j * 8) * C + c0 + tx];
  __syncthreads();
#pragma unroll
  for (int j = 0; j < 4; ++j)
    out[(size_t)(c0 + ty + j * 8) * R + r0 + tx] =
        __float2bfloat16(tile[tx][ty + j * 8]);
}

// ----------------------------------------------------------- rope cos/sin table
__global__ __launch_bounds__(256) void k_ropetab(float* __restrict__ cosT,
                                                 float* __restrict__ sinT) {
  int idx = blockIdx.x * 256 + threadIdx.x;  // 2048*64
  int t = idx >> 6, i = idx & 63;
  float inv = expf(-logf(10000.0f) * (float)i * (1.0f / 64.0f));
  float fr = (float)t * inv;
  cosT[idx] = cosf(fr);
  sinT[idx] = sinf(fr);
}

// ---------------------------- apply rope to q,k in place (vectorized, 8 d/thread)
__global__ __launch_bounds__(256) void k_rope(bf16* __restrict__ qkv,
                                              const float* __restrict__ cosT,
                                              const float* __restrict__ sinT) {
  int t = blockIdx.x * 256 + threadIdx.x;  // 2^20 threads
  int d0 = (t & 7) * 8;
  int qk = (t >> 3) & 1;
  int h = (t >> 4) & 15;
  int s = (t >> 8) & 2047;
  int b = (t >> 19) & 1;
  bf16* base = qkv + (size_t)(b * 2048 + s) * 6144 + qk * 2048 + h * 128;
  bx8 lo = *(const bx8*)(base + d0);
  bx8 hi = *(const bx8*)(base + 64 + d0);
  float4 ca = *(const float4*)&cosT[s * 64 + d0];
  float4 cb = *(const float4*)&cosT[s * 64 + d0 + 4];
  float4 sa = *(const float4*)&sinT[s * 64 + d0];
  float4 sb = *(const float4*)&sinT[s * 64 + d0 + 4];
  float c[8] = {ca.x, ca.y, ca.z, ca.w, cb.x, cb.y, cb.z, cb.w};
  float si[8] = {sa.x, sa.y, sa.z, sa.w, sb.x, sb.y, sb.z, sb.w};
  bx8 olo, ohi;
#pragma unroll
  for (int e = 0; e < 8; ++e) {
    float t1 = bf2f(lo[e]), t2 = bf2f(hi[e]);
    olo[e] = f2bf(t1 * c[e] - t2 * si[e]);
    ohi[e] = f2bf(t1 * si[e] + t2 * c[e]);
  }
  *(bx8*)(base + d0) = olo;
  *(bx8*)(base + 64 + d0) = ohi;
}

// -------------------------------------- V: [b,s,h,d] slice of qkv -> [b,h,d,s]
__global__ void k_vtrans(const bf16* __restrict__ qkv, bf16* __restrict__ vT) {
  __shared__ bf16 tile[32][33];
  int s0 = blockIdx.x * 32, d0 = blockIdx.y * 32, bh = blockIdx.z;
  int b = bh >> 4, h = bh & 15;
  int tx = threadIdx.x, ty = threadIdx.y;
#pragma unroll
  for (int j = 0; j < 4; ++j)
    tile[ty + j * 8][tx] =
        qkv[(size_t)(b * 2048 + s0 + ty + j * 8) * 6144 + 4096 + h * 128 + d0 + tx];
  __syncthreads();
#pragma unroll
  for (int j = 0; j < 4; ++j)
    vT[(size_t)(bh * 128 + d0 + ty + j * 8) * 2048 + s0 + tx] = tile[tx][ty + j * 8];
}

// --------------------- 128x128 GEMM (m97 structure, proven ~900 TF) ----------
__global__ __launch_bounds__(256) void k_gemm_bt(
    const bf16* __restrict__ A, const bf16* __restrict__ BT,
    const float* __restrict__ bias, void* __restrict__ Cp, int M, int N, int K,
    int out_bf16) {
  __shared__ __align__(16) bf16 As[128 * 64];
  __shared__ __align__(16) bf16 Bs[128 * 64];
  const int tid = threadIdx.x;
  const int m0 = blockIdx.y * 128, n0 = blockIdx.x * 128;
  const int lane = tid & 63, w = tid >> 6;
  const int lr = lane & 15, lg = lane >> 4;
  const int wr = w >> 1, wc = w & 1;

  fx4 acc[4][4];
#pragma unroll
  for (int m = 0; m < 4; ++m)
#pragma unroll
    for (int n = 0; n < 4; ++n) acc[m][n] = (fx4)(0.0f);

  for (int kt = 0; kt < K; kt += 64) {
#pragma unroll
    for (int q = 0; q < 4; ++q) {
      const int slot = q * 256 + tid;
      const int row = slot >> 3, u = slot & 7;
      const int us = (u ^ (row & 7)) * 8;
      GLD16(&As[slot * 8], A + (size_t)(m0 + row) * K + kt + us);
      GLD16(&Bs[slot * 8], BT + (size_t)(n0 + row) * K + kt + us);
    }
    __syncthreads();
#pragma unroll
    for (int ks = 0; ks < 2; ++ks) {
      bx8 af[4], bf[4];
#pragma unroll
      for (int m = 0; m < 4; ++m) {
        const int r = wr * 64 + m * 16 + lr;
        const int u = ((ks * 4 + lg) ^ (lr & 7)) * 8;
        af[m] = *(const bx8*)&As[r * 64 + u];
      }
#pragma unroll
      for (int n = 0; n < 4; ++n) {
        const int r = wc * 64 + n * 16 + lr;
        const int u = ((ks * 4 + lg) ^ (lr & 7)) * 8;
        bf[n] = *(const bx8*)&Bs[r * 64 + u];
      }
#pragma unroll
      for (int m = 0; m < 4; ++m)
#pragma unroll
        for (int n = 0; n < 4; ++n)
          acc[m][n] =
              __builtin_amdgcn_mfma_f32_16x16x32_bf16(af[m], bf[n], acc[m][n], 0, 0, 0);
    }
    __syncthreads();
  }

  float bv[4];
#pragma unroll
  for (int n = 0; n < 4; ++n) bv[n] = bias[n0 + wc * 64 + n * 16 + lr];

#pragma unroll
  for (int m = 0; m < 4; ++m)
#pragma unroll
    for (int n = 0; n < 4; ++n) {
      const int col = n0 + wc * 64 + n * 16 + lr;
#pragma unroll
      for (int j = 0; j < 4; ++j) {
        const int row = m0 + wr * 64 + m * 16 + lg * 4 + j;
        const float v = acc[m][n][j] + bv[n];
        if (out_bf16)
          ((bf16*)Cp)[(size_t)row * N + col] = __float2bfloat16(v);
        else
          ((float*)Cp)[(size_t)row * N + col] = v;
      }
    }
}

// ------------------------------------------------------------- flash attention
// Split-KV, disjoint plain-store partials. KVBLK=64, dbuf + vmcnt(4).
// LDS = 2x16KB (Ks) + 16KB (Ps) = 48KB -> 3 blocks/CU -> all 768 blocks
// co-resident in ONE generation (launch_bounds(256,3): 3 waves/SIMD).
// 768 blocks = 24 units x 32 bh. qt<=7: full row (2qt+2 tiles) -> ctx.
// qt>=8: chunk0 = tiles 0..15 -> O0/l0, chunk1 = tiles 16..2qt+1 -> O1/l1.
#define ATT_SL2E 0.12751740f  // (1/sqrt(128)) * log2(e)

__global__ __launch_bounds__(256, 3) void k_attn2(
    const bf16* __restrict__ qkv, const bf16* __restrict__ vT,
    bf16* __restrict__ ctx, float* __restrict__ O0, float* __restrict__ O1,
    float* __restrict__ l0, float* __restrict__ l1) {
  __shared__ __align__(16) bf16 Ks[2][64 * 128];
  __shared__ __align__(16) bf16 Ps[4][32 * 64];
  const int tid = threadIdx.x;
  const int lane = tid & 63, w = tid >> 6;
  const int lr = lane & 15, lg = lane >> 4;
  const int bid = blockIdx.x;
  const int u = bid >> 5, bh = bid & 31;
  const int b = bh >> 4, h = bh & 15;
  int qt, t0, t1;
  if (u < 8) {            // chunk0 of qt=8..15 : 16 tiles (kv 0..1023)
    qt = 8 + u; t0 = 0; t1 = 16;
  } else if (u < 16) {    // chunk1 of qt=15..8 : 2qt-14 tiles (kv 1024..)
    qt = 23 - u; t0 = 16; t1 = 2 * qt + 2;
  } else {                // full row qt=7..0 : 2qt+2 tiles
    qt = 23 - u; t0 = 0; t1 = 2 * qt + 2;
  }
  const int single = (u >= 16);
  const int nt = t1 - t0;

  const bf16* kbase = qkv + (size_t)b * 2048 * 6144 + 2048 + h * 128;
  const bf16* vbase = vT + (size_t)(b * 16 + h) * 128 * 2048;

  auto STAGE = [&](int bufi, int kt) {
    const int kv0 = kt * 64;
#pragma unroll
    for (int q = 0; q < 4; ++q) {
      const int slot = q * 256 + tid;
      const int row = slot >> 4, uu = slot & 15;
      GLD16(&Ks[bufi][slot * 8],
            kbase + (size_t)(kv0 + row) * 6144 + ((uu ^ (row & 15)) * 8));
    }
  };

  // Q fragments: 32 rows/wave
  const bf16* qbase =
      qkv + (size_t)(b * 2048 + qt * 128 + w * 32) * 6144 + h * 128;
  bx8 qf[2][4];
#pragma unroll
  for (int m = 0; m < 2; ++m)
#pragma unroll
    for (int ks = 0; ks < 4; ++ks)
      qf[m][ks] = *(const bx8*)(qbase + (size_t)(m * 16 + lr) * 6144 + ks * 32 + lg * 8);

  bx8 vones;
#pragma unroll
  for (int e = 0; e < 8; ++e) vones[e] = (short)0x3F80;  // bf16 1.0

  fx4 oacc[2][8], lacc[2];
#pragma unroll
  for (int m = 0; m < 2; ++m) {
    lacc[m] = (fx4)(0.0f);
#pragma unroll
    for (int d = 0; d < 8; ++d) oacc[m][d] = (fx4)(0.0f);
  }

  const int qrow0 = qt * 128 + w * 32;

  STAGE(0, t0);
  for (int i = 0; i < nt; ++i) {
    const int kt = t0 + i;
    const int cur = i & 1;
    if (i + 1 < nt) {
      STAGE(cur ^ 1, kt + 1);
      asm volatile("s_waitcnt vmcnt(4)" ::: "memory");
    } else {
      asm volatile("s_waitcnt vmcnt(0)" ::: "memory");
    }
    __builtin_amdgcn_s_barrier();
    asm volatile("" ::: "memory");

    const int kv0 = kt * 64;
    if (kv0 <= qrow0 + 31) {  // else wave fully masked (barriers stay outside)
      // ---- QK^T over this 64-kv tile
      fx4 sacc[2][4];
#pragma unroll
      for (int n = 0; n < 4; ++n) {
        sacc[0][n] = (fx4)(0.0f);
        sacc[1][n] = (fx4)(0.0f);
      }
      __builtin_amdgcn_s_setprio(1);
#pragma unroll
      for (int n = 0; n < 4; ++n) {
        const int r = n * 16 + lr;
#pragma unroll
        for (int ks = 0; ks < 4; ++ks) {
          const bx8 kf = *(const bx8*)&Ks[cur][r * 128 + (((ks * 4 + lg) ^ lr) * 8)];
          sacc[0][n] =
              __builtin_amdgcn_mfma_f32_16x16x32_bf16(qf[0][ks], kf, sacc[0][n], 0, 0, 0);
          sacc[1][n] =
              __builtin_amdgcn_mfma_f32_16x16x32_bf16(qf[1][ks], kf, sacc[1][n], 0, 0, 0);
        }
      }
      __builtin_amdgcn_s_setprio(0);

      // ---- static-max softmax: p = exp2(min(s*scale*log2e, 60)); masked -> 0
      const bool needmask = (kv0 + 63) > qrow0;  // wave-uniform
#pragma unroll
      for (int n = 0; n < 4; ++n) {
        const int kvi = kv0 + n * 16 + lr;
#pragma unroll
        for (int m = 0; m < 2; ++m)
#pragma unroll
          for (int j = 0; j < 4; ++j) {
            float v = sacc[m][n][j] * ATT_SL2E;
            if (needmask) {
              const int qi = qrow0 + m * 16 + lg * 4 + j;
              if (kvi > qi) v = -200.0f;
            }
            const float p = exp2f(fminf(v, 60.0f));
            const int r = m * 16 + lg * 4 + j, c = n * 16 + lr;
            const int c2 = (c & 7) | (((c >> 3) ^ (r & 7)) << 3);
            Ps[w][r * 64 + c2] = __float2bfloat16(p);
          }
      }

      // ---- PV (V direct from global, L2-resident) + row-sum via ones-MFMA
      __builtin_amdgcn_s_setprio(1);
#pragma unroll
      for (int ks2 = 0; ks2 < 2; ++ks2) {
        const int uu = ((ks2 * 4 + lg) ^ (lr & 7)) * 8;
        const bx8 pf0 = *(const bx8*)&Ps[w][(0 * 16 + lr) * 64 + uu];
        const bx8 pf1 = *(const bx8*)&Ps[w][(1 * 16 + lr) * 64 + uu];
        lacc[0] = __builtin_amdgcn_mfma_f32_16x16x32_bf16(pf0, vones, lacc[0], 0, 0, 0);
        lacc[1] = __builtin_amdgcn_mfma_f32_16x16x32_bf16(pf1, vones, lacc[1], 0, 0, 0);
#pragma unroll
        for (int dn = 0; dn < 8; ++dn) {
          const bx8 vf = *(const bx8*)(vbase + (size_t)(dn * 16 + lr) * 2048 + kv0 +
                                       ks2 * 32 + lg * 8);
          oacc[0][dn] =
              __builtin_amdgcn_mfma_f32_16x16x32_bf16(pf0, vf, oacc[0][dn], 0, 0, 0);
          oacc[1][dn] =
              __builtin_amdgcn_mfma_f32_16x16x32_bf16(pf1, vf, oacc[1][dn], 0, 0, 0);
        }
      }
      __builtin_amdgcn_s_setprio(0);
    }
    __builtin_amdgcn_s_barrier();  // all waves done reading Ks[cur]
    asm volatile("" ::: "memory");
  }

  if (single) {
    float rl[2][4];
#pragma unroll
    for (int m = 0; m < 2; ++m)
#pragma unroll
      for (int j = 0; j < 4; ++j) rl[m][j] = 1.0f / lacc[m][j];
#pragma unroll
    for (int m = 0; m < 2; ++m)
#pragma unroll
      for (int dn = 0; dn < 8; ++dn)
#pragma unroll
        for (int j = 0; j < 4; ++j) {
          const int row = qt * 128 + w * 32 + m * 16 + lg * 4 + j;
          ctx[(size_t)(b * 2048 + row) * 2048 + h * 128 + dn * 16 + lr] =
              __float2bfloat16(oacc[m][dn][j] * rl[m][j]);
        }
  } else {
    // disjoint plain-store partials (each element written exactly once)
    float* Op = (u < 8) ? O0 : O1;
    float* lp = (u < 8) ? l0 : l1;
    float* obase =
        Op + (((size_t)(b * 16 + h)) * 1024 + (qt * 128 - 1024 + w * 32)) * 128;
#pragma unroll
    for (int m = 0; m < 2; ++m)
#pragma unroll
      for (int dn = 0; dn < 8; ++dn)
#pragma unroll
        for (int j = 0; j < 4; ++j)
          obase[(m * 16 + lg * 4 + j) * 128 + dn * 16 + lr] = oacc[m][dn][j];
    if (lr == 0) {
      float* lbase =
          lp + ((size_t)(b * 16 + h)) * 1024 + (qt * 128 - 1024 + w * 32);
#pragma unroll
      for (int m = 0; m < 2; ++m)
#pragma unroll
        for (int j = 0; j < 4; ++j) lbase[m * 16 + lg * 4 + j] = lacc[m][j];
    }
  }
}

// ----------------------- combine split rows: ctx = (O0+O1)/(l0+l1), s>=1024
__global__ __launch_bounds__(256) void k_comb(const float* __restrict__ O0,
                                              const float* __restrict__ O1,
                                              const float* __restrict__ l0,
                                              const float* __restrict__ l1,
                                              bf16* __restrict__ ctx) {
  const int idx = blockIdx.x * 256 + threadIdx.x;  // 524288 threads x 8 floats
  const size_t base = (size_t)idx * 8;
  const size_t rowi = base >> 7;  // (b*16+h)*1024 + (s-1024)
  const float rl = 1.0f / (l0[rowi] + l1[rowi]);
  const float4 a0 = *(const float4*)&O0[base];
  const float4 b0 = *(const float4*)&O0[base + 4];
  const float4 a1 = *(const float4*)&O1[base];
  const float4 b1 = *(const float4*)&O1[base + 4];
  const int d = (int)(base & 127);
  const int s = (int)(rowi & 1023);
  const int bh = (int)(rowi >> 10);
  const int b = bh >> 4, h = bh & 15;
  bf16 o[8] = {__float2bfloat16((a0.x + a1.x) * rl), __float2bfloat16((a0.y + a1.y) * rl),
               __float2bfloat16((a0.z + a1.z) * rl), __float2bfloat16((a0.w + a1.w) * rl),
               __float2bfloat16((b0.x + b1.x) * rl), __float2bfloat16((b0.y + b1.y) * rl),
               __float2bfloat16((b0.z + b1.z) * rl), __float2bfloat16((b0.w + b1.w) * rl)};
  bf16* p = ctx + (size_t)(b * 2048 + 1024 + s) * 2048 + h * 128 + d;
  *(ushort4*)p = *(ushort4*)o;
  *(ushort4*)(p + 4) = *(ushort4*)(o + 4);
}

// ------------------------------------------------------------------- launcher
extern "C" void kernel_launch(void* const* d_in, const int* in_sizes, int n_in,
                              void* d_out, int out_size, void* d_ws, size_t ws_size,
                              hipStream_t stream) {
  const float* x = (const float*)d_in[0];
  const float* Wqkv = (const float*)d_in[1];
  const float* bqkv = (const float*)d_in[2];
  const float* Wout = (const float*)d_in[3];
  const float* bout = (const float*)d_in[4];
  float* out = (float*)d_out;

  char* ws = (char*)d_ws;
  bf16* xb    = (bf16*)(ws + 0);          // 16 MiB (dead after QKV GEMM)
  bf16* wqkvT = (bf16*)(ws + 16777216);   // 24 MiB (dead after QKV GEMM)
  bf16* woutT = (bf16*)(ws + 41943040);   // 8 MiB
  bf16* qkvb  = (bf16*)(ws + 50331648);   // 48 MiB
  bf16* vTb   = (bf16*)(ws + 100663296);  // 16 MiB
  bf16* ctxb  = (bf16*)(ws + 117440512);  // 16 MiB
  float* cosT = (float*)(ws + 134217728); // 512 KiB
  float* sinT = (float*)(ws + 134742016); // 512 KiB
  // split-KV partials overlap the dead xb/wqkvT regions:
  float* O0 = (float*)(ws + 0);               // 16 MiB
  float* O1 = (float*)(ws + 16777216);        // 16 MiB
  float* l0 = (float*)(ws + 33554432);        // 128 KiB
  float* l1 = (float*)(ws + 33685504);        // 128 KiB

  k_cast<<<8192, 256, 0, stream>>>(x, xb, 2097152);
  k_tcast<<<dim3(192, 64), dim3(32, 8), 0, stream>>>(Wqkv, wqkvT, 2048, 6144);
  k_tcast<<<dim3(64, 64), dim3(32, 8), 0, stream>>>(Wout, woutT, 2048, 2048);
  k_ropetab<<<512, 256, 0, stream>>>(cosT, sinT);
  // QKV = x @ Wqkv + b (m97 128^2 structure)
  k_gemm_bt<<<dim3(48, 32), 256, 0, stream>>>(xb, wqkvT, bqkv, qkvb, 4096, 6144,
                                              2048, 1);
  k_rope<<<4096, 256, 0, stream>>>(qkvb, cosT, sinT);
  k_vtrans<<<dim3(64, 4, 32), dim3(32, 8), 0, stream>>>(qkvb, vTb);
  // split-KV flash attention: 768 blocks, all co-resident (3 blocks/CU)
  k_attn2<<<768, 256, 0, stream>>>(qkvb, vTb, ctxb, O0, O1, l0, l1);
  k_comb<<<2048, 256, 0, stream>>>(O0, O1, l0, l1, ctxb);
  // out = ctx @ Wout + bout (fp32 out)
  k_gemm_bt<<<dim3(16, 32), 256, 0, stream>>>(ctxb, woutT, bout, out, 4096, 2048,
                                              2048, 0);
}

// Round 10
// 326.340 us; speedup vs baseline: 1.6010x; 1.6010x over previous
//
#include <hip/hip_runtime.h>
#include <hip/hip_bf16.h>

typedef __attribute__((ext_vector_type(4))) float fx4;
typedef __attribute__((ext_vector_type(8))) short bx8;
typedef __hip_bfloat16 bf16;

#define GLD16(dst, src)                                                        \
  __builtin_amdgcn_global_load_lds(                                            \
      (__attribute__((address_space(1))) void*)(src),                          \
      (__attribute__((address_space(3))) void*)(dst), 16, 0, 0)

__device__ inline float bf2f(short s_) {
  unsigned int u = ((unsigned int)(unsigned short)s_) << 16;
  float f;
  __builtin_memcpy(&f, &u, 4);
  return f;
}
__device__ inline short f2bf(float f) {
  __hip_bfloat16 h = __float2bfloat16(f);
  short r;
  __builtin_memcpy(&r, &h, 2);
  return r;
}

#define ATT_SL2E 0.12751740f  // (1/sqrt(128)) * log2(e), pre-folded into Q

// ---------------------------------------------------------------- cast x->bf16
__global__ __launch_bounds__(256) void k_cast(const float* __restrict__ in,
                                              bf16* __restrict__ out, int n4) {
  int i = blockIdx.x * 256 + threadIdx.x;
  if (i >= n4) return;
  float4 v = reinterpret_cast<const float4*>(in)[i];
  bf16 t[4] = {__float2bfloat16(v.x), __float2bfloat16(v.y),
               __float2bfloat16(v.z), __float2bfloat16(v.w)};
  reinterpret_cast<ushort4*>(out)[i] = *reinterpret_cast<ushort4*>(t);
}

// ------------------------------------------- transpose-cast fp32 RxC -> bf16 CxR
__global__ void k_tcast(const float* __restrict__ in, bf16* __restrict__ out,
                        int R, int C) {
  __shared__ float tile[32][33];
  int c0 = blockIdx.x * 32, r0 = blockIdx.y * 32;
  int tx = threadIdx.x, ty = threadIdx.y;
#pragma unroll
  for (int j = 0; j < 4; ++j)
    tile[ty + j * 8][tx] = in[(size_t)(r0 + ty + j * 8) * C + c0 + tx];
  __syncthreads();
#pragma unroll
  for (int j = 0; j < 4; ++j)
    out[(size_t)(c0 + ty + j * 8) * R + r0 + tx] =
        __float2bfloat16(tile[tx][ty + j * 8]);
}

// ----------------------------------------------------------- rope cos/sin table
__global__ __launch_bounds__(256) void k_ropetab(float* __restrict__ cosT,
                                                 float* __restrict__ sinT) {
  int idx = blockIdx.x * 256 + threadIdx.x;  // 2048*64
  int t = idx >> 6, i = idx & 63;
  float inv = expf(-logf(10000.0f) * (float)i * (1.0f / 64.0f));
  float fr = (float)t * inv;
  cosT[idx] = cosf(fr);
  sinT[idx] = sinf(fr);
}

// ------------- apply rope to q,k in place; q additionally pre-scaled by SL2E
__global__ __launch_bounds__(256) void k_rope(bf16* __restrict__ qkv,
                                              const float* __restrict__ cosT,
                                              const float* __restrict__ sinT) {
  int t = blockIdx.x * 256 + threadIdx.x;  // 2^20 threads
  int d0 = (t & 7) * 8;
  int qk = (t >> 3) & 1;
  int h = (t >> 4) & 15;
  int s = (t >> 8) & 2047;
  int b = (t >> 19) & 1;
  const float sc = qk ? 1.0f : ATT_SL2E;  // q gets the softmax scale baked in
  bf16* base = qkv + (size_t)(b * 2048 + s) * 6144 + qk * 2048 + h * 128;
  bx8 lo = *(const bx8*)(base + d0);
  bx8 hi = *(const bx8*)(base + 64 + d0);
  float4 ca = *(const float4*)&cosT[s * 64 + d0];
  float4 cb = *(const float4*)&cosT[s * 64 + d0 + 4];
  float4 sa = *(const float4*)&sinT[s * 64 + d0];
  float4 sb = *(const float4*)&sinT[s * 64 + d0 + 4];
  float c[8] = {ca.x, ca.y, ca.z, ca.w, cb.x, cb.y, cb.z, cb.w};
  float si[8] = {sa.x, sa.y, sa.z, sa.w, sb.x, sb.y, sb.z, sb.w};
  bx8 olo, ohi;
#pragma unroll
  for (int e = 0; e < 8; ++e) {
    float t1 = bf2f(lo[e]), t2 = bf2f(hi[e]);
    olo[e] = f2bf((t1 * c[e] - t2 * si[e]) * sc);
    ohi[e] = f2bf((t1 * si[e] + t2 * c[e]) * sc);
  }
  *(bx8*)(base + d0) = olo;
  *(bx8*)(base + 64 + d0) = ohi;
}

// -------------------------------------- V: [b,s,h,d] slice of qkv -> [b,h,d,s]
__global__ void k_vtrans(const bf16* __restrict__ qkv, bf16* __restrict__ vT) {
  __shared__ bf16 tile[32][33];
  int s0 = blockIdx.x * 32, d0 = blockIdx.y * 32, bh = blockIdx.z;
  int b = bh >> 4, h = bh & 15;
  int tx = threadIdx.x, ty = threadIdx.y;
#pragma unroll
  for (int j = 0; j < 4; ++j)
    tile[ty + j * 8][tx] =
        qkv[(size_t)(b * 2048 + s0 + ty + j * 8) * 6144 + 4096 + h * 128 + d0 + tx];
  __syncthreads();
#pragma unroll
  for (int j = 0; j < 4; ++j)
    vT[(size_t)(bh * 128 + d0 + ty + j * 8) * 2048 + s0 + tx] = tile[tx][ty + j * 8];
}

// --------------------- 128x128 GEMM (m97 structure, proven ~900 TF) ----------
__global__ __launch_bounds__(256) void k_gemm_bt(
    const bf16* __restrict__ A, const bf16* __restrict__ BT,
    const float* __restrict__ bias, void* __restrict__ Cp, int M, int N, int K,
    int out_bf16) {
  __shared__ __align__(16) bf16 As[128 * 64];
  __shared__ __align__(16) bf16 Bs[128 * 64];
  const int tid = threadIdx.x;
  const int m0 = blockIdx.y * 128, n0 = blockIdx.x * 128;
  const int lane = tid & 63, w = tid >> 6;
  const int lr = lane & 15, lg = lane >> 4;
  const int wr = w >> 1, wc = w & 1;

  fx4 acc[4][4];
#pragma unroll
  for (int m = 0; m < 4; ++m)
#pragma unroll
    for (int n = 0; n < 4; ++n) acc[m][n] = (fx4)(0.0f);

  for (int kt = 0; kt < K; kt += 64) {
#pragma unroll
    for (int q = 0; q < 4; ++q) {
      const int slot = q * 256 + tid;
      const int row = slot >> 3, u = slot & 7;
      const int us = (u ^ (row & 7)) * 8;
      GLD16(&As[slot * 8], A + (size_t)(m0 + row) * K + kt + us);
      GLD16(&Bs[slot * 8], BT + (size_t)(n0 + row) * K + kt + us);
    }
    __syncthreads();
#pragma unroll
    for (int ks = 0; ks < 2; ++ks) {
      bx8 af[4], bf[4];
#pragma unroll
      for (int m = 0; m < 4; ++m) {
        const int r = wr * 64 + m * 16 + lr;
        const int u = ((ks * 4 + lg) ^ (lr & 7)) * 8;
        af[m] = *(const bx8*)&As[r * 64 + u];
      }
#pragma unroll
      for (int n = 0; n < 4; ++n) {
        const int r = wc * 64 + n * 16 + lr;
        const int u = ((ks * 4 + lg) ^ (lr & 7)) * 8;
        bf[n] = *(const bx8*)&Bs[r * 64 + u];
      }
#pragma unroll
      for (int m = 0; m < 4; ++m)
#pragma unroll
        for (int n = 0; n < 4; ++n)
          acc[m][n] =
              __builtin_amdgcn_mfma_f32_16x16x32_bf16(af[m], bf[n], acc[m][n], 0, 0, 0);
    }
    __syncthreads();
  }

  float bv[4];
#pragma unroll
  for (int n = 0; n < 4; ++n) bv[n] = bias[n0 + wc * 64 + n * 16 + lr];

#pragma unroll
  for (int m = 0; m < 4; ++m)
#pragma unroll
    for (int n = 0; n < 4; ++n) {
      const int col = n0 + wc * 64 + n * 16 + lr;
#pragma unroll
      for (int j = 0; j < 4; ++j) {
        const int row = m0 + wr * 64 + m * 16 + lg * 4 + j;
        const float v = acc[m][n][j] + bv[n];
        if (out_bf16)
          ((bf16*)Cp)[(size_t)row * N + col] = __float2bfloat16(v);
        else
          ((float*)Cp)[(size_t)row * N + col] = v;
      }
    }
}

// ------------------------------------------------------------- flash attention
// R6-proven config: split-KV, disjoint plain-store partials, KVBLK=128
// (two 64-halves), K dbuf + vmcnt(8), V direct global (L2), static-max
// softmax (scale pre-folded into Q), row-sum via ones-MFMA, 2 blocks/CU.
__global__ __launch_bounds__(256, 2) void k_attn2(
    const bf16* __restrict__ qkv, const bf16* __restrict__ vT,
    bf16* __restrict__ ctx, float* __restrict__ O0, float* __restrict__ O1,
    float* __restrict__ l0, float* __restrict__ l1) {
  __shared__ __align__(16) bf16 Ks[2][128 * 128];
  __shared__ __align__(16) bf16 Ps[4][32 * 64];
  const int tid = threadIdx.x;
  const int lane = tid & 63, w = tid >> 6;
  const int lr = lane & 15, lg = lane >> 4;
  const int bid = blockIdx.x;
  const int u = bid >> 5, bh = bid & 31;
  const int b = bh >> 4, h = bh & 15;
  int qt, t0, t1;
  if (u < 8) {            // chunk0 of qt=8..15 : 8 tiles
    qt = 8 + u; t0 = 0; t1 = 8;
  } else if (u < 16) {    // chunk1 of qt=15..8 : qt-7 tiles
    qt = 23 - u; t0 = 8; t1 = qt + 1;
  } else {                // full row qt=7..0 : qt+1 tiles
    qt = 23 - u; t0 = 0; t1 = qt + 1;
  }
  const int single = (u >= 16);
  const int nt = t1 - t0;

  const bf16* kbase = qkv + (size_t)b * 2048 * 6144 + 2048 + h * 128;
  const bf16* vbase = vT + (size_t)(b * 16 + h) * 128 * 2048;

  auto STAGE = [&](int bufi, int kt) {
    const int kv0 = kt * 128;
#pragma unroll
    for (int q = 0; q < 8; ++q) {
      const int slot = q * 256 + tid;
      const int row = slot >> 4, uu = slot & 15;
      GLD16(&Ks[bufi][slot * 8],
            kbase + (size_t)(kv0 + row) * 6144 + ((uu ^ (row & 15)) * 8));
    }
  };

  // Q fragments: 32 rows/wave (Q already has SL2E folded in)
  const bf16* qbase =
      qkv + (size_t)(b * 2048 + qt * 128 + w * 32) * 6144 + h * 128;
  bx8 qf[2][4];
#pragma unroll
  for (int m = 0; m < 2; ++m)
#pragma unroll
    for (int ks = 0; ks < 4; ++ks)
      qf[m][ks] = *(const bx8*)(qbase + (size_t)(m * 16 + lr) * 6144 + ks * 32 + lg * 8);

  bx8 vones;
#pragma unroll
  for (int e = 0; e < 8; ++e) vones[e] = (short)0x3F80;  // bf16 1.0

  fx4 oacc[2][8], lacc[2];
#pragma unroll
  for (int m = 0; m < 2; ++m) {
    lacc[m] = (fx4)(0.0f);
#pragma unroll
    for (int d = 0; d < 8; ++d) oacc[m][d] = (fx4)(0.0f);
  }

  const int qrow0 = qt * 128 + w * 32;

  STAGE(0, t0);
  for (int i = 0; i < nt; ++i) {
    const int kt = t0 + i;
    const int cur = i & 1;
    if (i + 1 < nt) {
      STAGE(cur ^ 1, kt + 1);
      asm volatile("s_waitcnt vmcnt(8)" ::: "memory");
    } else {
      asm volatile("s_waitcnt vmcnt(0)" ::: "memory");
    }
    __builtin_amdgcn_s_barrier();
    asm volatile("" ::: "memory");

#pragma unroll
    for (int h2 = 0; h2 < 2; ++h2) {
      const int kv0 = kt * 128 + h2 * 64;
      if (kv0 > qrow0 + 31) continue;  // wave fully masked (wave-uniform)

      // ---- QK^T over this 64-kv half (result already in log2 units)
      fx4 sacc[2][4];
#pragma unroll
      for (int n = 0; n < 4; ++n) {
        sacc[0][n] = (fx4)(0.0f);
        sacc[1][n] = (fx4)(0.0f);
      }
      __builtin_amdgcn_s_setprio(1);
#pragma unroll
      for (int n = 0; n < 4; ++n) {
        const int r = h2 * 64 + n * 16 + lr;
#pragma unroll
        for (int ks = 0; ks < 4; ++ks) {
          const bx8 kf = *(const bx8*)&Ks[cur][r * 128 + (((ks * 4 + lg) ^ lr) * 8)];
          sacc[0][n] =
              __builtin_amdgcn_mfma_f32_16x16x32_bf16(qf[0][ks], kf, sacc[0][n], 0, 0, 0);
          sacc[1][n] =
              __builtin_amdgcn_mfma_f32_16x16x32_bf16(qf[1][ks], kf, sacc[1][n], 0, 0, 0);
        }
      }
      __builtin_amdgcn_s_setprio(0);

      // ---- static-max softmax: p = exp2(min(v, 60)); masked -> 0
      const bool needmask = (kv0 + 63) > qrow0;  // wave-uniform
#pragma unroll
      for (int n = 0; n < 4; ++n) {
        const int kvi = kv0 + n * 16 + lr;
#pragma unroll
        for (int m = 0; m < 2; ++m)
#pragma unroll
          for (int j = 0; j < 4; ++j) {
            float v = sacc[m][n][j];
            if (needmask) {
              const int qi = qrow0 + m * 16 + lg * 4 + j;
              if (kvi > qi) v = -200.0f;
            }
            const float p = exp2f(fminf(v, 60.0f));
            const int r = m * 16 + lg * 4 + j, c = n * 16 + lr;
            const int c2 = (c & 7) | (((c >> 3) ^ (r & 7)) << 3);
            Ps[w][r * 64 + c2] = __float2bfloat16(p);
          }
      }

      // ---- PV (V direct from global, L2-resident) + row-sum via ones-MFMA
      __builtin_amdgcn_s_setprio(1);
#pragma unroll
      for (int ks2 = 0; ks2 < 2; ++ks2) {
        const int uu = ((ks2 * 4 + lg) ^ (lr & 7)) * 8;
        const bx8 pf0 = *(const bx8*)&Ps[w][(0 * 16 + lr) * 64 + uu];
        const bx8 pf1 = *(const bx8*)&Ps[w][(1 * 16 + lr) * 64 + uu];
        lacc[0] = __builtin_amdgcn_mfma_f32_16x16x32_bf16(pf0, vones, lacc[0], 0, 0, 0);
        lacc[1] = __builtin_amdgcn_mfma_f32_16x16x32_bf16(pf1, vones, lacc[1], 0, 0, 0);
#pragma unroll
        for (int dn = 0; dn < 8; ++dn) {
          const bx8 vf = *(const bx8*)(vbase + (size_t)(dn * 16 + lr) * 2048 + kv0 +
                                       ks2 * 32 + lg * 8);
          oacc[0][dn] =
              __builtin_amdgcn_mfma_f32_16x16x32_bf16(pf0, vf, oacc[0][dn], 0, 0, 0);
          oacc[1][dn] =
              __builtin_amdgcn_mfma_f32_16x16x32_bf16(pf1, vf, oacc[1][dn], 0, 0, 0);
        }
      }
      __builtin_amdgcn_s_setprio(0);
    }
    __builtin_amdgcn_s_barrier();  // all waves done reading Ks[cur]
    asm volatile("" ::: "memory");
  }

  if (single) {
    float rl[2][4];
#pragma unroll
    for (int m = 0; m < 2; ++m)
#pragma unroll
      for (int j = 0; j < 4; ++j) rl[m][j] = 1.0f / lacc[m][j];
#pragma unroll
    for (int m = 0; m < 2; ++m)
#pragma unroll
      for (int dn = 0; dn < 8; ++dn)
#pragma unroll
        for (int j = 0; j < 4; ++j) {
          const int row = qt * 128 + w * 32 + m * 16 + lg * 4 + j;
          ctx[(size_t)(b * 2048 + row) * 2048 + h * 128 + dn * 16 + lr] =
              __float2bfloat16(oacc[m][dn][j] * rl[m][j]);
        }
  } else {
    // disjoint plain-store partials (each element written exactly once)
    float* Op = (u < 8) ? O0 : O1;
    float* lp = (u < 8) ? l0 : l1;
    float* obase =
        Op + (((size_t)(b * 16 + h)) * 1024 + (qt * 128 - 1024 + w * 32)) * 128;
#pragma unroll
    for (int m = 0; m < 2; ++m)
#pragma unroll
      for (int dn = 0; dn < 8; ++dn)
#pragma unroll
        for (int j = 0; j < 4; ++j)
          obase[(m * 16 + lg * 4 + j) * 128 + dn * 16 + lr] = oacc[m][dn][j];
    if (lr == 0) {
      float* lbase =
          lp + ((size_t)(b * 16 + h)) * 1024 + (qt * 128 - 1024 + w * 32);
#pragma unroll
      for (int m = 0; m < 2; ++m)
#pragma unroll
        for (int j = 0; j < 4; ++j) lbase[m * 16 + lg * 4 + j] = lacc[m][j];
    }
  }
}

// ----------------------- combine split rows: ctx = (O0+O1)/(l0+l1), s>=1024
__global__ __launch_bounds__(256) void k_comb(const float* __restrict__ O0,
                                              const float* __restrict__ O1,
                                              const float* __restrict__ l0,
                                              const float* __restrict__ l1,
                                              bf16* __restrict__ ctx) {
  const int idx = blockIdx.x * 256 + threadIdx.x;  // 524288 threads x 8 floats
  const size_t base = (size_t)idx * 8;
  const size_t rowi = base >> 7;  // (b*16+h)*1024 + (s-1024)
  const float rl = 1.0f / (l0[rowi] + l1[rowi]);
  const float4 a0 = *(const float4*)&O0[base];
  const float4 b0 = *(const float4*)&O0[base + 4];
  const float4 a1 = *(const float4*)&O1[base];
  const float4 b1 = *(const float4*)&O1[base + 4];
  const int d = (int)(base & 127);
  const int s = (int)(rowi & 1023);
  const int bh = (int)(rowi >> 10);
  const int b = bh >> 4, h = bh & 15;
  bf16 o[8] = {__float2bfloat16((a0.x + a1.x) * rl), __float2bfloat16((a0.y + a1.y) * rl),
               __float2bfloat16((a0.z + a1.z) * rl), __float2bfloat16((a0.w + a1.w) * rl),
               __float2bfloat16((b0.x + b1.x) * rl), __float2bfloat16((b0.y + b1.y) * rl),
               __float2bfloat16((b0.z + b1.z) * rl), __float2bfloat16((b0.w + b1.w) * rl)};
  bf16* p = ctx + (size_t)(b * 2048 + 1024 + s) * 2048 + h * 128 + d;
  *(ushort4*)p = *(ushort4*)o;
  *(ushort4*)(p + 4) = *(ushort4*)(o + 4);
}

// ------------------------------------------------------------------- launcher
extern "C" void kernel_launch(void* const* d_in, const int* in_sizes, int n_in,
                              void* d_out, int out_size, void* d_ws, size_t ws_size,
                              hipStream_t stream) {
  const float* x = (const float*)d_in[0];
  const float* Wqkv = (const float*)d_in[1];
  const float* bqkv = (const float*)d_in[2];
  const float* Wout = (const float*)d_in[3];
  const float* bout = (const float*)d_in[4];
  float* out = (float*)d_out;

  char* ws = (char*)d_ws;
  bf16* xb    = (bf16*)(ws + 0);          // 16 MiB (dead after QKV GEMM)
  bf16* wqkvT = (bf16*)(ws + 16777216);   // 24 MiB (dead after QKV GEMM)
  bf16* woutT = (bf16*)(ws + 41943040);   // 8 MiB
  bf16* qkvb  = (bf16*)(ws + 50331648);   // 48 MiB
  bf16* vTb   = (bf16*)(ws + 100663296);  // 16 MiB
  bf16* ctxb  = (bf16*)(ws + 117440512);  // 16 MiB
  float* cosT = (float*)(ws + 134217728); // 512 KiB
  float* sinT = (float*)(ws + 134742016); // 512 KiB
  // split-KV partials overlap the dead xb/wqkvT regions:
  float* O0 = (float*)(ws + 0);               // 16 MiB
  float* O1 = (float*)(ws + 16777216);        // 16 MiB
  float* l0 = (float*)(ws + 33554432);        // 128 KiB
  float* l1 = (float*)(ws + 33685504);        // 128 KiB

  k_cast<<<8192, 256, 0, stream>>>(x, xb, 2097152);
  k_tcast<<<dim3(192, 64), dim3(32, 8), 0, stream>>>(Wqkv, wqkvT, 2048, 6144);
  k_tcast<<<dim3(64, 64), dim3(32, 8), 0, stream>>>(Wout, woutT, 2048, 2048);
  k_ropetab<<<512, 256, 0, stream>>>(cosT, sinT);
  // QKV = x @ Wqkv + b (m97 128^2 structure)
  k_gemm_bt<<<dim3(48, 32), 256, 0, stream>>>(xb, wqkvT, bqkv, qkvb, 4096, 6144,
                                              2048, 1);
  k_rope<<<4096, 256, 0, stream>>>(qkvb, cosT, sinT);
  k_vtrans<<<dim3(64, 4, 32), dim3(32, 8), 0, stream>>>(qkvb, vTb);
  // split-KV flash attention: 768 blocks, plain-store partials
  k_attn2<<<768, 256, 0, stream>>>(qkvb, vTb, ctxb, O0, O1, l0, l1);
  k_comb<<<2048, 256, 0, stream>>>(O0, O1, l0, l1, ctxb);
  // out = ctx @ Wout + bout (fp32 out)
  k_gemm_bt<<<dim3(16, 32), 256, 0, stream>>>(ctxb, woutT, bout, out, 4096, 2048,
                                              2048, 0);
}

// Round 11
// 316.513 us; speedup vs baseline: 1.6507x; 1.0310x over previous
//
#include <hip/hip_runtime.h>
#include <hip/hip_bf16.h>

typedef __attribute__((ext_vector_type(4))) float fx4;
typedef __attribute__((ext_vector_type(8))) short bx8;
typedef __hip_bfloat16 bf16;

#define GLD16(dst, src)                                                        \
  __builtin_amdgcn_global_load_lds(                                            \
      (__attribute__((address_space(1))) void*)(src),                          \
      (__attribute__((address_space(3))) void*)(dst), 16, 0, 0)

__device__ inline float bf2f(short s_) {
  unsigned int u = ((unsigned int)(unsigned short)s_) << 16;
  float f;
  __builtin_memcpy(&f, &u, 4);
  return f;
}
__device__ inline short f2bf(float f) {
  __hip_bfloat16 h = __float2bfloat16(f);
  short r;
  __builtin_memcpy(&r, &h, 2);
  return r;
}

#define ATT_SL2E 0.12751740f  // (1/sqrt(128)) * log2(e), pre-folded into Q

// ---------------------------------------------------------------- cast x->bf16
__global__ __launch_bounds__(256) void k_cast(const float* __restrict__ in,
                                              bf16* __restrict__ out, int n4) {
  int i = blockIdx.x * 256 + threadIdx.x;
  if (i >= n4) return;
  float4 v = reinterpret_cast<const float4*>(in)[i];
  bf16 t[4] = {__float2bfloat16(v.x), __float2bfloat16(v.y),
               __float2bfloat16(v.z), __float2bfloat16(v.w)};
  reinterpret_cast<ushort4*>(out)[i] = *reinterpret_cast<ushort4*>(t);
}

// ------------------------------------------- transpose-cast fp32 RxC -> bf16 CxR
__global__ void k_tcast(const float* __restrict__ in, bf16* __restrict__ out,
                        int R, int C) {
  __shared__ float tile[32][33];
  int c0 = blockIdx.x * 32, r0 = blockIdx.y * 32;
  int tx = threadIdx.x, ty = threadIdx.y;
#pragma unroll
  for (int j = 0; j < 4; ++j)
    tile[ty + j * 8][tx] = in[(size_t)(r0 + ty + j * 8) * C + c0 + tx];
  __syncthreads();
#pragma unroll
  for (int j = 0; j < 4; ++j)
    out[(size_t)(c0 + ty + j * 8) * R + r0 + tx] =
        __float2bfloat16(tile[tx][ty + j * 8]);
}

// ----------------------------------------------------------- rope cos/sin table
__global__ __launch_bounds__(256) void k_ropetab(float* __restrict__ cosT,
                                                 float* __restrict__ sinT) {
  int idx = blockIdx.x * 256 + threadIdx.x;  // 2048*64
  int t = idx >> 6, i = idx & 63;
  float inv = expf(-logf(10000.0f) * (float)i * (1.0f / 64.0f));
  float fr = (float)t * inv;
  cosT[idx] = cosf(fr);
  sinT[idx] = sinf(fr);
}

// ------------- apply rope to q,k in place; q additionally pre-scaled by SL2E
__global__ __launch_bounds__(256) void k_rope(bf16* __restrict__ qkv,
                                              const float* __restrict__ cosT,
                                              const float* __restrict__ sinT) {
  int t = blockIdx.x * 256 + threadIdx.x;  // 2^20 threads
  int d0 = (t & 7) * 8;
  int qk = (t >> 3) & 1;
  int h = (t >> 4) & 15;
  int s = (t >> 8) & 2047;
  int b = (t >> 19) & 1;
  const float sc = qk ? 1.0f : ATT_SL2E;  // q gets the softmax scale baked in
  bf16* base = qkv + (size_t)(b * 2048 + s) * 6144 + qk * 2048 + h * 128;
  bx8 lo = *(const bx8*)(base + d0);
  bx8 hi = *(const bx8*)(base + 64 + d0);
  float4 ca = *(const float4*)&cosT[s * 64 + d0];
  float4 cb = *(const float4*)&cosT[s * 64 + d0 + 4];
  float4 sa = *(const float4*)&sinT[s * 64 + d0];
  float4 sb = *(const float4*)&sinT[s * 64 + d0 + 4];
  float c[8] = {ca.x, ca.y, ca.z, ca.w, cb.x, cb.y, cb.z, cb.w};
  float si[8] = {sa.x, sa.y, sa.z, sa.w, sb.x, sb.y, sb.z, sb.w};
  bx8 olo, ohi;
#pragma unroll
  for (int e = 0; e < 8; ++e) {
    float t1 = bf2f(lo[e]), t2 = bf2f(hi[e]);
    olo[e] = f2bf((t1 * c[e] - t2 * si[e]) * sc);
    ohi[e] = f2bf((t1 * si[e] + t2 * c[e]) * sc);
  }
  *(bx8*)(base + d0) = olo;
  *(bx8*)(base + 64 + d0) = ohi;
}

// -------------------------------------- V: [b,s,h,d] slice of qkv -> [b,h,d,s]
__global__ void k_vtrans(const bf16* __restrict__ qkv, bf16* __restrict__ vT) {
  __shared__ bf16 tile[32][33];
  int s0 = blockIdx.x * 32, d0 = blockIdx.y * 32, bh = blockIdx.z;
  int b = bh >> 4, h = bh & 15;
  int tx = threadIdx.x, ty = threadIdx.y;
#pragma unroll
  for (int j = 0; j < 4; ++j)
    tile[ty + j * 8][tx] =
        qkv[(size_t)(b * 2048 + s0 + ty + j * 8) * 6144 + 4096 + h * 128 + d0 + tx];
  __syncthreads();
#pragma unroll
  for (int j = 0; j < 4; ++j)
    vT[(size_t)(bh * 128 + d0 + ty + j * 8) * 2048 + s0 + tx] = tile[tx][ty + j * 8];
}

// --------------------- 128x128 GEMM (m97 structure, proven ~900 TF) ----------
__global__ __launch_bounds__(256) void k_gemm_bt(
    const bf16* __restrict__ A, const bf16* __restrict__ BT,
    const float* __restrict__ bias, void* __restrict__ Cp, int M, int N, int K,
    int out_bf16) {
  __shared__ __align__(16) bf16 As[128 * 64];
  __shared__ __align__(16) bf16 Bs[128 * 64];
  const int tid = threadIdx.x;
  const int m0 = blockIdx.y * 128, n0 = blockIdx.x * 128;
  const int lane = tid & 63, w = tid >> 6;
  const int lr = lane & 15, lg = lane >> 4;
  const int wr = w >> 1, wc = w & 1;

  fx4 acc[4][4];
#pragma unroll
  for (int m = 0; m < 4; ++m)
#pragma unroll
    for (int n = 0; n < 4; ++n) acc[m][n] = (fx4)(0.0f);

  for (int kt = 0; kt < K; kt += 64) {
#pragma unroll
    for (int q = 0; q < 4; ++q) {
      const int slot = q * 256 + tid;
      const int row = slot >> 3, u = slot & 7;
      const int us = (u ^ (row & 7)) * 8;
      GLD16(&As[slot * 8], A + (size_t)(m0 + row) * K + kt + us);
      GLD16(&Bs[slot * 8], BT + (size_t)(n0 + row) * K + kt + us);
    }
    __syncthreads();
#pragma unroll
    for (int ks = 0; ks < 2; ++ks) {
      bx8 af[4], bf[4];
#pragma unroll
      for (int m = 0; m < 4; ++m) {
        const int r = wr * 64 + m * 16 + lr;
        const int u = ((ks * 4 + lg) ^ (lr & 7)) * 8;
        af[m] = *(const bx8*)&As[r * 64 + u];
      }
#pragma unroll
      for (int n = 0; n < 4; ++n) {
        const int r = wc * 64 + n * 16 + lr;
        const int u = ((ks * 4 + lg) ^ (lr & 7)) * 8;
        bf[n] = *(const bx8*)&Bs[r * 64 + u];
      }
#pragma unroll
      for (int m = 0; m < 4; ++m)
#pragma unroll
        for (int n = 0; n < 4; ++n)
          acc[m][n] =
              __builtin_amdgcn_mfma_f32_16x16x32_bf16(af[m], bf[n], acc[m][n], 0, 0, 0);
    }
    __syncthreads();
  }

  float bv[4];
#pragma unroll
  for (int n = 0; n < 4; ++n) bv[n] = bias[n0 + wc * 64 + n * 16 + lr];

#pragma unroll
  for (int m = 0; m < 4; ++m)
#pragma unroll
    for (int n = 0; n < 4; ++n) {
      const int col = n0 + wc * 64 + n * 16 + lr;
#pragma unroll
      for (int j = 0; j < 4; ++j) {
        const int row = m0 + wr * 64 + m * 16 + lg * 4 + j;
        const float v = acc[m][n][j] + bv[n];
        if (out_bf16)
          ((bf16*)Cp)[(size_t)row * N + col] = __float2bfloat16(v);
        else
          ((float*)Cp)[(size_t)row * N + col] = v;
      }
    }
}

// ------------------------------------------------------------- flash attention
// Split-KV, disjoint plain-store partials. KVBLK=64 dbuf + vmcnt(4).
// LDS = 2x16KB (Ks) + 16KB (Ps) = 48KB -> HW allows 3 blocks/CU; 768 blocks
// = one generation. launch_bounds(256,2) so the allocator keeps ~124 VGPRs
// (R8 lesson: bounding to 3 waves/SIMD caps VGPR at 84 -> acc spill).
__global__ __launch_bounds__(256, 2) void k_attn2(
    const bf16* __restrict__ qkv, const bf16* __restrict__ vT,
    bf16* __restrict__ ctx, float* __restrict__ O0, float* __restrict__ O1,
    float* __restrict__ l0, float* __restrict__ l1) {
  __shared__ __align__(16) bf16 Ks[2][64 * 128];
  __shared__ __align__(16) bf16 Ps[4][32 * 64];
  const int tid = threadIdx.x;
  const int lane = tid & 63, w = tid >> 6;
  const int lr = lane & 15, lg = lane >> 4;
  const int bid = blockIdx.x;
  const int u = bid >> 5, bh = bid & 31;
  const int b = bh >> 4, h = bh & 15;
  int qt, t0, t1;                    // t in units of 64 kv
  if (u < 8) {            // chunk0 of qt=8..15 : 16 tiles (kv 0..1023)
    qt = 8 + u; t0 = 0; t1 = 16;
  } else if (u < 16) {    // chunk1 of qt=15..8 : 2qt-14 tiles (kv 1024..)
    qt = 23 - u; t0 = 16; t1 = 2 * qt + 2;
  } else {                // full row qt=7..0 : 2qt+2 tiles
    qt = 23 - u; t0 = 0; t1 = 2 * qt + 2;
  }
  const int single = (u >= 16);
  const int nt = t1 - t0;

  const bf16* kbase = qkv + (size_t)b * 2048 * 6144 + 2048 + h * 128;
  const bf16* vbase = vT + (size_t)(b * 16 + h) * 128 * 2048;

  auto STAGE = [&](int bufi, int kt) {
    const int kv0 = kt * 64;
#pragma unroll
    for (int q = 0; q < 4; ++q) {
      const int slot = q * 256 + tid;
      const int row = slot >> 4, uu = slot & 15;
      GLD16(&Ks[bufi][slot * 8],
            kbase + (size_t)(kv0 + row) * 6144 + ((uu ^ (row & 15)) * 8));
    }
  };

  // Q fragments: 32 rows/wave (Q already has SL2E folded in)
  const bf16* qbase =
      qkv + (size_t)(b * 2048 + qt * 128 + w * 32) * 6144 + h * 128;
  bx8 qf[2][4];
#pragma unroll
  for (int m = 0; m < 2; ++m)
#pragma unroll
    for (int ks = 0; ks < 4; ++ks)
      qf[m][ks] = *(const bx8*)(qbase + (size_t)(m * 16 + lr) * 6144 + ks * 32 + lg * 8);

  bx8 vones;
#pragma unroll
  for (int e = 0; e < 8; ++e) vones[e] = (short)0x3F80;  // bf16 1.0

  fx4 oacc[2][8], lacc[2];
#pragma unroll
  for (int m = 0; m < 2; ++m) {
    lacc[m] = (fx4)(0.0f);
#pragma unroll
    for (int d = 0; d < 8; ++d) oacc[m][d] = (fx4)(0.0f);
  }

  const int qrow0 = qt * 128 + w * 32;

  STAGE(0, t0);
  for (int i = 0; i < nt; ++i) {
    const int kt = t0 + i;
    const int cur = i & 1;
    if (i + 1 < nt) {
      STAGE(cur ^ 1, kt + 1);
      asm volatile("s_waitcnt vmcnt(4)" ::: "memory");
    } else {
      asm volatile("s_waitcnt vmcnt(0)" ::: "memory");
    }
    __builtin_amdgcn_s_barrier();
    asm volatile("" ::: "memory");

    const int kv0 = kt * 64;
    if (kv0 <= qrow0 + 31) {  // else wave fully masked (barriers stay outside)
      // ---- QK^T over this 64-kv tile (result already in log2 units)
      fx4 sacc[2][4];
#pragma unroll
      for (int n = 0; n < 4; ++n) {
        sacc[0][n] = (fx4)(0.0f);
        sacc[1][n] = (fx4)(0.0f);
      }
      __builtin_amdgcn_s_setprio(1);
#pragma unroll
      for (int n = 0; n < 4; ++n) {
        const int r = n * 16 + lr;
#pragma unroll
        for (int ks = 0; ks < 4; ++ks) {
          const bx8 kf = *(const bx8*)&Ks[cur][r * 128 + (((ks * 4 + lg) ^ lr) * 8)];
          sacc[0][n] =
              __builtin_amdgcn_mfma_f32_16x16x32_bf16(qf[0][ks], kf, sacc[0][n], 0, 0, 0);
          sacc[1][n] =
              __builtin_amdgcn_mfma_f32_16x16x32_bf16(qf[1][ks], kf, sacc[1][n], 0, 0, 0);
        }
      }
      __builtin_amdgcn_s_setprio(0);

      // ---- static-max softmax: p = exp2(min(v, 60)); masked -> 0
      const bool needmask = (kv0 + 63) > qrow0;  // wave-uniform
#pragma unroll
      for (int n = 0; n < 4; ++n) {
        const int kvi = kv0 + n * 16 + lr;
#pragma unroll
        for (int m = 0; m < 2; ++m)
#pragma unroll
          for (int j = 0; j < 4; ++j) {
            float v = sacc[m][n][j];
            if (needmask) {
              const int qi = qrow0 + m * 16 + lg * 4 + j;
              if (kvi > qi) v = -200.0f;
            }
            const float p = exp2f(fminf(v, 60.0f));
            const int r = m * 16 + lg * 4 + j, c = n * 16 + lr;
            const int c2 = (c & 7) | (((c >> 3) ^ (r & 7)) << 3);
            Ps[w][r * 64 + c2] = __float2bfloat16(p);
          }
      }

      // ---- PV (V direct from global, L2-resident) + row-sum via ones-MFMA
      __builtin_amdgcn_s_setprio(1);
#pragma unroll
      for (int ks2 = 0; ks2 < 2; ++ks2) {
        const int uu = ((ks2 * 4 + lg) ^ (lr & 7)) * 8;
        const bx8 pf0 = *(const bx8*)&Ps[w][(0 * 16 + lr) * 64 + uu];
        const bx8 pf1 = *(const bx8*)&Ps[w][(1 * 16 + lr) * 64 + uu];
        lacc[0] = __builtin_amdgcn_mfma_f32_16x16x32_bf16(pf0, vones, lacc[0], 0, 0, 0);
        lacc[1] = __builtin_amdgcn_mfma_f32_16x16x32_bf16(pf1, vones, lacc[1], 0, 0, 0);
#pragma unroll
        for (int dn = 0; dn < 8; ++dn) {
          const bx8 vf = *(const bx8*)(vbase + (size_t)(dn * 16 + lr) * 2048 + kv0 +
                                       ks2 * 32 + lg * 8);
          oacc[0][dn] =
              __builtin_amdgcn_mfma_f32_16x16x32_bf16(pf0, vf, oacc[0][dn], 0, 0, 0);
          oacc[1][dn] =
              __builtin_amdgcn_mfma_f32_16x16x32_bf16(pf1, vf, oacc[1][dn], 0, 0, 0);
        }
      }
      __builtin_amdgcn_s_setprio(0);
    }
    __builtin_amdgcn_s_barrier();  // all waves done reading Ks[cur]
    asm volatile("" ::: "memory");
  }

  if (single) {
    float rl[2][4];
#pragma unroll
    for (int m = 0; m < 2; ++m)
#pragma unroll
      for (int j = 0; j < 4; ++j) rl[m][j] = 1.0f / lacc[m][j];
#pragma unroll
    for (int m = 0; m < 2; ++m)
#pragma unroll
      for (int dn = 0; dn < 8; ++dn)
#pragma unroll
        for (int j = 0; j < 4; ++j) {
          const int row = qt * 128 + w * 32 + m * 16 + lg * 4 + j;
          ctx[(size_t)(b * 2048 + row) * 2048 + h * 128 + dn * 16 + lr] =
              __float2bfloat16(oacc[m][dn][j] * rl[m][j]);
        }
  } else {
    // disjoint plain-store partials (each element written exactly once)
    float* Op = (u < 8) ? O0 : O1;
    float* lp = (u < 8) ? l0 : l1;
    float* obase =
        Op + (((size_t)(b * 16 + h)) * 1024 + (qt * 128 - 1024 + w * 32)) * 128;
#pragma unroll
    for (int m = 0; m < 2; ++m)
#pragma unroll
      for (int dn = 0; dn < 8; ++dn)
#pragma unroll
        for (int j = 0; j < 4; ++j)
          obase[(m * 16 + lg * 4 + j) * 128 + dn * 16 + lr] = oacc[m][dn][j];
    if (lr == 0) {
      float* lbase =
          lp + ((size_t)(b * 16 + h)) * 1024 + (qt * 128 - 1024 + w * 32);
#pragma unroll
      for (int m = 0; m < 2; ++m)
#pragma unroll
        for (int j = 0; j < 4; ++j) lbase[m * 16 + lg * 4 + j] = lacc[m][j];
    }
  }
}

// ----------------------- combine split rows: ctx = (O0+O1)/(l0+l1), s>=1024
__global__ __launch_bounds__(256) void k_comb(const float* __restrict__ O0,
                                              const float* __restrict__ O1,
                                              const float* __restrict__ l0,
                                              const float* __restrict__ l1,
                                              bf16* __restrict__ ctx) {
  const int idx = blockIdx.x * 256 + threadIdx.x;  // 524288 threads x 8 floats
  const size_t base = (size_t)idx * 8;
  const size_t rowi = base >> 7;  // (b*16+h)*1024 + (s-1024)
  const float rl = 1.0f / (l0[rowi] + l1[rowi]);
  const float4 a0 = *(const float4*)&O0[base];
  const float4 b0 = *(const float4*)&O0[base + 4];
  const float4 a1 = *(const float4*)&O1[base];
  const float4 b1 = *(const float4*)&O1[base + 4];
  const int d = (int)(base & 127);
  const int s = (int)(rowi & 1023);
  const int bh = (int)(rowi >> 10);
  const int b = bh >> 4, h = bh & 15;
  bf16 o[8] = {__float2bfloat16((a0.x + a1.x) * rl), __float2bfloat16((a0.y + a1.y) * rl),
               __float2bfloat16((a0.z + a1.z) * rl), __float2bfloat16((a0.w + a1.w) * rl),
               __float2bfloat16((b0.x + b1.x) * rl), __float2bfloat16((b0.y + b1.y) * rl),
               __float2bfloat16((b0.z + b1.z) * rl), __float2bfloat16((b0.w + b1.w) * rl)};
  bf16* p = ctx + (size_t)(b * 2048 + 1024 + s) * 2048 + h * 128 + d;
  *(ushort4*)p = *(ushort4*)o;
  *(ushort4*)(p + 4) = *(ushort4*)(o + 4);
}

// ------------------------------------------------------------------- launcher
extern "C" void kernel_launch(void* const* d_in, const int* in_sizes, int n_in,
                              void* d_out, int out_size, void* d_ws, size_t ws_size,
                              hipStream_t stream) {
  const float* x = (const float*)d_in[0];
  const float* Wqkv = (const float*)d_in[1];
  const float* bqkv = (const float*)d_in[2];
  const float* Wout = (const float*)d_in[3];
  const float* bout = (const float*)d_in[4];
  float* out = (float*)d_out;

  char* ws = (char*)d_ws;
  bf16* xb    = (bf16*)(ws + 0);          // 16 MiB (dead after QKV GEMM)
  bf16* wqkvT = (bf16*)(ws + 16777216);   // 24 MiB (dead after QKV GEMM)
  bf16* woutT = (bf16*)(ws + 41943040);   // 8 MiB
  bf16* qkvb  = (bf16*)(ws + 50331648);   // 48 MiB
  bf16* vTb   = (bf16*)(ws + 100663296);  // 16 MiB
  bf16* ctxb  = (bf16*)(ws + 117440512);  // 16 MiB
  float* cosT = (float*)(ws + 134217728); // 512 KiB
  float* sinT = (float*)(ws + 134742016); // 512 KiB
  // split-KV partials overlap the dead xb/wqkvT regions:
  float* O0 = (float*)(ws + 0);               // 16 MiB
  float* O1 = (float*)(ws + 16777216);        // 16 MiB
  float* l0 = (float*)(ws + 33554432);        // 128 KiB
  float* l1 = (float*)(ws + 33685504);        // 128 KiB

  k_cast<<<8192, 256, 0, stream>>>(x, xb, 2097152);
  k_tcast<<<dim3(192, 64), dim3(32, 8), 0, stream>>>(Wqkv, wqkvT, 2048, 6144);
  k_tcast<<<dim3(64, 64), dim3(32, 8), 0, stream>>>(Wout, woutT, 2048, 2048);
  k_ropetab<<<512, 256, 0, stream>>>(cosT, sinT);
  // QKV = x @ Wqkv + b (m97 128^2 structure)
  k_gemm_bt<<<dim3(48, 32), 256, 0, stream>>>(xb, wqkvT, bqkv, qkvb, 4096, 6144,
                                              2048, 1);
  k_rope<<<4096, 256, 0, stream>>>(qkvb, cosT, sinT);
  k_vtrans<<<dim3(64, 4, 32), dim3(32, 8), 0, stream>>>(qkvb, vTb);
  // split-KV flash attention: 768 blocks, 48KB LDS -> 3 blocks/CU
  k_attn2<<<768, 256, 0, stream>>>(qkvb, vTb, ctxb, O0, O1, l0, l1);
  k_comb<<<2048, 256, 0, stream>>>(O0, O1, l0, l1, ctxb);
  // out = ctx @ Wout + bout (fp32 out)
  k_gemm_bt<<<dim3(16, 32), 256, 0, stream>>>(ctxb, woutT, bout, out, 4096, 2048,
                                              2048, 0);
}

// Round 12
// 309.422 us; speedup vs baseline: 1.6885x; 1.0229x over previous
//
#include <hip/hip_runtime.h>
#include <hip/hip_bf16.h>

typedef __attribute__((ext_vector_type(4))) float fx4;
typedef __attribute__((ext_vector_type(8))) short bx8;
typedef __hip_bfloat16 bf16;

#define GLD16(dst, src)                                                        \
  __builtin_amdgcn_global_load_lds(                                            \
      (__attribute__((address_space(1))) void*)(src),                          \
      (__attribute__((address_space(3))) void*)(dst), 16, 0, 0)

__device__ inline float bf2f(short s_) {
  unsigned int u = ((unsigned int)(unsigned short)s_) << 16;
  float f;
  __builtin_memcpy(&f, &u, 4);
  return f;
}
__device__ inline short f2bf(float f) {
  __hip_bfloat16 h = __float2bfloat16(f);
  short r;
  __builtin_memcpy(&r, &h, 2);
  return r;
}

#define ATT_SL2E 0.12751740f  // (1/sqrt(128)) * log2(e), pre-folded into Q

// ---------------------------------------------------------------- cast x->bf16
__global__ __launch_bounds__(256) void k_cast(const float* __restrict__ in,
                                              bf16* __restrict__ out, int n4) {
  int i = blockIdx.x * 256 + threadIdx.x;
  if (i >= n4) return;
  float4 v = reinterpret_cast<const float4*>(in)[i];
  bf16 t[4] = {__float2bfloat16(v.x), __float2bfloat16(v.y),
               __float2bfloat16(v.z), __float2bfloat16(v.w)};
  reinterpret_cast<ushort4*>(out)[i] = *reinterpret_cast<ushort4*>(t);
}

// ------------------------------------------- transpose-cast fp32 RxC -> bf16 CxR
__global__ void k_tcast(const float* __restrict__ in, bf16* __restrict__ out,
                        int R, int C) {
  __shared__ float tile[32][33];
  int c0 = blockIdx.x * 32, r0 = blockIdx.y * 32;
  int tx = threadIdx.x, ty = threadIdx.y;
#pragma unroll
  for (int j = 0; j < 4; ++j)
    tile[ty + j * 8][tx] = in[(size_t)(r0 + ty + j * 8) * C + c0 + tx];
  __syncthreads();
#pragma unroll
  for (int j = 0; j < 4; ++j)
    out[(size_t)(c0 + ty + j * 8) * R + r0 + tx] =
        __float2bfloat16(tile[tx][ty + j * 8]);
}

// ----------------------------------------------------------- rope cos/sin table
__global__ __launch_bounds__(256) void k_ropetab(float* __restrict__ cosT,
                                                 float* __restrict__ sinT) {
  int idx = blockIdx.x * 256 + threadIdx.x;  // 2048*64
  int t = idx >> 6, i = idx & 63;
  float inv = expf(-logf(10000.0f) * (float)i * (1.0f / 64.0f));
  float fr = (float)t * inv;
  cosT[idx] = cosf(fr);
  sinT[idx] = sinf(fr);
}

// -------------------------------------- V: [b,s,h,d] slice of qkv -> [b,h,d,s]
__global__ void k_vtrans(const bf16* __restrict__ qkv, bf16* __restrict__ vT) {
  __shared__ bf16 tile[32][33];
  int s0 = blockIdx.x * 32, d0 = blockIdx.y * 32, bh = blockIdx.z;
  int b = bh >> 4, h = bh & 15;
  int tx = threadIdx.x, ty = threadIdx.y;
#pragma unroll
  for (int j = 0; j < 4; ++j)
    tile[ty + j * 8][tx] =
        qkv[(size_t)(b * 2048 + s0 + ty + j * 8) * 6144 + 4096 + h * 128 + d0 + tx];
  __syncthreads();
#pragma unroll
  for (int j = 0; j < 4; ++j)
    vT[(size_t)(bh * 128 + d0 + ty + j * 8) * 2048 + s0 + tx] = tile[tx][ty + j * 8];
}

// --------------------- 128x128 GEMM (m97 structure, proven ~900 TF) ----------
// rope=1 (QKV GEMM only, bf16 out): fused RoPE epilogue. Each block spans one
// head's 128 cols; (c, c+64) pairs are exchanged through the As/Bs LDS
// (dead after the K-loop -> aliased, LDS footprint unchanged). Numerics match
// the old separate k_rope (bf16-round -> fp32 rope -> bf16-round).
__global__ __launch_bounds__(256) void k_gemm_bt(
    const bf16* __restrict__ A, const bf16* __restrict__ BT,
    const float* __restrict__ bias, void* __restrict__ Cp, int M, int N, int K,
    int out_bf16, int rope, const float* __restrict__ cosT,
    const float* __restrict__ sinT) {
  __shared__ __align__(16) bf16 smem[128 * 128];  // As | Bs ; epilogue: Ex
  bf16* As = smem;
  bf16* Bs = smem + 128 * 64;
  const int tid = threadIdx.x;
  const int m0 = blockIdx.y * 128, n0 = blockIdx.x * 128;
  const int lane = tid & 63, w = tid >> 6;
  const int lr = lane & 15, lg = lane >> 4;
  const int wr = w >> 1, wc = w & 1;

  fx4 acc[4][4];
#pragma unroll
  for (int m = 0; m < 4; ++m)
#pragma unroll
    for (int n = 0; n < 4; ++n) acc[m][n] = (fx4)(0.0f);

  for (int kt = 0; kt < K; kt += 64) {
#pragma unroll
    for (int q = 0; q < 4; ++q) {
      const int slot = q * 256 + tid;
      const int row = slot >> 3, u = slot & 7;
      const int us = (u ^ (row & 7)) * 8;
      GLD16(&As[slot * 8], A + (size_t)(m0 + row) * K + kt + us);
      GLD16(&Bs[slot * 8], BT + (size_t)(n0 + row) * K + kt + us);
    }
    __syncthreads();
#pragma unroll
    for (int ks = 0; ks < 2; ++ks) {
      bx8 af[4], bf[4];
#pragma unroll
      for (int m = 0; m < 4; ++m) {
        const int r = wr * 64 + m * 16 + lr;
        const int u = ((ks * 4 + lg) ^ (lr & 7)) * 8;
        af[m] = *(const bx8*)&As[r * 64 + u];
      }
#pragma unroll
      for (int n = 0; n < 4; ++n) {
        const int r = wc * 64 + n * 16 + lr;
        const int u = ((ks * 4 + lg) ^ (lr & 7)) * 8;
        bf[n] = *(const bx8*)&Bs[r * 64 + u];
      }
#pragma unroll
      for (int m = 0; m < 4; ++m)
#pragma unroll
        for (int n = 0; n < 4; ++n)
          acc[m][n] =
              __builtin_amdgcn_mfma_f32_16x16x32_bf16(af[m], bf[n], acc[m][n], 0, 0, 0);
    }
    __syncthreads();
  }

  float bv[4];
#pragma unroll
  for (int n = 0; n < 4; ++n) bv[n] = bias[n0 + wc * 64 + n * 16 + lr];

  const bool do_rope = rope && (n0 < 4096);
  if (do_rope) {
    // stage bf16(acc+bias) into the exchange buffer Ex[row][col] (128x128)
    bf16(*Ex)[128] = (bf16(*)[128])smem;
#pragma unroll
    for (int m = 0; m < 4; ++m)
#pragma unroll
      for (int n = 0; n < 4; ++n) {
        const int col = wc * 64 + n * 16 + lr;
#pragma unroll
        for (int j = 0; j < 4; ++j) {
          const int row = wr * 64 + m * 16 + lg * 4 + j;
          Ex[row][col] = __float2bfloat16(acc[m][n][j] + bv[n]);
        }
      }
    __syncthreads();
    // apply rope: pairs (c, c+64), c in [0,64). 1024 bx8-chunks / 256 threads.
    const float sc = (n0 < 2048) ? ATT_SL2E : 1.0f;  // q gets softmax scale
    bf16* Cb = (bf16*)Cp;
#pragma unroll
    for (int i = 0; i < 4; ++i) {
      const int wk = tid + 256 * i;
      const int row = wk >> 3, c0 = (wk & 7) * 8;
      const int s = (m0 + row) & 2047;
      bx8 lo = *(const bx8*)&Ex[row][c0];
      bx8 hi = *(const bx8*)&Ex[row][c0 + 64];
      float4 ca = *(const float4*)&cosT[s * 64 + c0];
      float4 cb = *(const float4*)&cosT[s * 64 + c0 + 4];
      float4 sa = *(const float4*)&sinT[s * 64 + c0];
      float4 sb = *(const float4*)&sinT[s * 64 + c0 + 4];
      float c[8] = {ca.x, ca.y, ca.z, ca.w, cb.x, cb.y, cb.z, cb.w};
      float si[8] = {sa.x, sa.y, sa.z, sa.w, sb.x, sb.y, sb.z, sb.w};
      bx8 olo, ohi;
#pragma unroll
      for (int e = 0; e < 8; ++e) {
        float t1 = bf2f(lo[e]), t2 = bf2f(hi[e]);
        olo[e] = f2bf((t1 * c[e] - t2 * si[e]) * sc);
        ohi[e] = f2bf((t1 * si[e] + t2 * c[e]) * sc);
      }
      *(bx8*)&Cb[(size_t)(m0 + row) * N + n0 + c0] = olo;
      *(bx8*)&Cb[(size_t)(m0 + row) * N + n0 + c0 + 64] = ohi;
    }
    return;
  }

#pragma unroll
  for (int m = 0; m < 4; ++m)
#pragma unroll
    for (int n = 0; n < 4; ++n) {
      const int col = n0 + wc * 64 + n * 16 + lr;
#pragma unroll
      for (int j = 0; j < 4; ++j) {
        const int row = m0 + wr * 64 + m * 16 + lg * 4 + j;
        const float v = acc[m][n][j] + bv[n];
        if (out_bf16)
          ((bf16*)Cp)[(size_t)row * N + col] = __float2bfloat16(v);
        else
          ((float*)Cp)[(size_t)row * N + col] = v;
      }
    }
}

// ------------------------------------------------------------- flash attention
// Split-KV, disjoint plain-store partials. KVBLK=64 dbuf + vmcnt(4).
// 48KB LDS -> 3 blocks/CU; launch_bounds(256,2) so allocator keeps ~124 VGPRs.
__global__ __launch_bounds__(256, 2) void k_attn2(
    const bf16* __restrict__ qkv, const bf16* __restrict__ vT,
    bf16* __restrict__ ctx, float* __restrict__ O0, float* __restrict__ O1,
    float* __restrict__ l0, float* __restrict__ l1) {
  __shared__ __align__(16) bf16 Ks[2][64 * 128];
  __shared__ __align__(16) bf16 Ps[4][32 * 64];
  const int tid = threadIdx.x;
  const int lane = tid & 63, w = tid >> 6;
  const int lr = lane & 15, lg = lane >> 4;
  const int bid = blockIdx.x;
  const int u = bid >> 5, bh = bid & 31;
  const int b = bh >> 4, h = bh & 15;
  int qt, t0, t1;                    // t in units of 64 kv
  if (u < 8) {            // chunk0 of qt=8..15 : 16 tiles (kv 0..1023)
    qt = 8 + u; t0 = 0; t1 = 16;
  } else if (u < 16) {    // chunk1 of qt=15..8 : 2qt-14 tiles (kv 1024..)
    qt = 23 - u; t0 = 16; t1 = 2 * qt + 2;
  } else {                // full row qt=7..0 : 2qt+2 tiles
    qt = 23 - u; t0 = 0; t1 = 2 * qt + 2;
  }
  const int single = (u >= 16);
  const int nt = t1 - t0;

  const bf16* kbase = qkv + (size_t)b * 2048 * 6144 + 2048 + h * 128;
  const bf16* vbase = vT + (size_t)(b * 16 + h) * 128 * 2048;

  auto STAGE = [&](int bufi, int kt) {
    const int kv0 = kt * 64;
#pragma unroll
    for (int q = 0; q < 4; ++q) {
      const int slot = q * 256 + tid;
      const int row = slot >> 4, uu = slot & 15;
      GLD16(&Ks[bufi][slot * 8],
            kbase + (size_t)(kv0 + row) * 6144 + ((uu ^ (row & 15)) * 8));
    }
  };

  // Q fragments: 32 rows/wave (Q already has SL2E folded in)
  const bf16* qbase =
      qkv + (size_t)(b * 2048 + qt * 128 + w * 32) * 6144 + h * 128;
  bx8 qf[2][4];
#pragma unroll
  for (int m = 0; m < 2; ++m)
#pragma unroll
    for (int ks = 0; ks < 4; ++ks)
      qf[m][ks] = *(const bx8*)(qbase + (size_t)(m * 16 + lr) * 6144 + ks * 32 + lg * 8);

  bx8 vones;
#pragma unroll
  for (int e = 0; e < 8; ++e) vones[e] = (short)0x3F80;  // bf16 1.0

  fx4 oacc[2][8], lacc[2];
#pragma unroll
  for (int m = 0; m < 2; ++m) {
    lacc[m] = (fx4)(0.0f);
#pragma unroll
    for (int d = 0; d < 8; ++d) oacc[m][d] = (fx4)(0.0f);
  }

  const int qrow0 = qt * 128 + w * 32;

  STAGE(0, t0);
  for (int i = 0; i < nt; ++i) {
    const int kt = t0 + i;
    const int cur = i & 1;
    if (i + 1 < nt) {
      STAGE(cur ^ 1, kt + 1);
      asm volatile("s_waitcnt vmcnt(4)" ::: "memory");
    } else {
      asm volatile("s_waitcnt vmcnt(0)" ::: "memory");
    }
    __builtin_amdgcn_s_barrier();
    asm volatile("" ::: "memory");

    const int kv0 = kt * 64;
    if (kv0 <= qrow0 + 31) {  // else wave fully masked (barriers stay outside)
      // ---- QK^T over this 64-kv tile (result already in log2 units)
      fx4 sacc[2][4];
#pragma unroll
      for (int n = 0; n < 4; ++n) {
        sacc[0][n] = (fx4)(0.0f);
        sacc[1][n] = (fx4)(0.0f);
      }
      __builtin_amdgcn_s_setprio(1);
#pragma unroll
      for (int n = 0; n < 4; ++n) {
        const int r = n * 16 + lr;
#pragma unroll
        for (int ks = 0; ks < 4; ++ks) {
          const bx8 kf = *(const bx8*)&Ks[cur][r * 128 + (((ks * 4 + lg) ^ lr) * 8)];
          sacc[0][n] =
              __builtin_amdgcn_mfma_f32_16x16x32_bf16(qf[0][ks], kf, sacc[0][n], 0, 0, 0);
          sacc[1][n] =
              __builtin_amdgcn_mfma_f32_16x16x32_bf16(qf[1][ks], kf, sacc[1][n], 0, 0, 0);
        }
      }
      __builtin_amdgcn_s_setprio(0);

      // ---- static-max softmax: p = exp2(min(v, 60)); masked -> 0
      const bool needmask = (kv0 + 63) > qrow0;  // wave-uniform
#pragma unroll
      for (int n = 0; n < 4; ++n) {
        const int kvi = kv0 + n * 16 + lr;
#pragma unroll
        for (int m = 0; m < 2; ++m)
#pragma unroll
          for (int j = 0; j < 4; ++j) {
            float v = sacc[m][n][j];
            if (needmask) {
              const int qi = qrow0 + m * 16 + lg * 4 + j;
              if (kvi > qi) v = -200.0f;
            }
            const float p = exp2f(fminf(v, 60.0f));
            const int r = m * 16 + lg * 4 + j, c = n * 16 + lr;
            const int c2 = (c & 7) | (((c >> 3) ^ (r & 7)) << 3);
            Ps[w][r * 64 + c2] = __float2bfloat16(p);
          }
      }

      // ---- PV (V direct from global, L2-resident) + row-sum via ones-MFMA
      __builtin_amdgcn_s_setprio(1);
#pragma unroll
      for (int ks2 = 0; ks2 < 2; ++ks2) {
        const int uu = ((ks2 * 4 + lg) ^ (lr & 7)) * 8;
        const bx8 pf0 = *(const bx8*)&Ps[w][(0 * 16 + lr) * 64 + uu];
        const bx8 pf1 = *(const bx8*)&Ps[w][(1 * 16 + lr) * 64 + uu];
        lacc[0] = __builtin_amdgcn_mfma_f32_16x16x32_bf16(pf0, vones, lacc[0], 0, 0, 0);
        lacc[1] = __builtin_amdgcn_mfma_f32_16x16x32_bf16(pf1, vones, lacc[1], 0, 0, 0);
#pragma unroll
        for (int dn = 0; dn < 8; ++dn) {
          const bx8 vf = *(const bx8*)(vbase + (size_t)(dn * 16 + lr) * 2048 + kv0 +
                                       ks2 * 32 + lg * 8);
          oacc[0][dn] =
              __builtin_amdgcn_mfma_f32_16x16x32_bf16(pf0, vf, oacc[0][dn], 0, 0, 0);
          oacc[1][dn] =
              __builtin_amdgcn_mfma_f32_16x16x32_bf16(pf1, vf, oacc[1][dn], 0, 0, 0);
        }
      }
      __builtin_amdgcn_s_setprio(0);
    }
    __builtin_amdgcn_s_barrier();  // all waves done reading Ks[cur]
    asm volatile("" ::: "memory");
  }

  if (single) {
    float rl[2][4];
#pragma unroll
    for (int m = 0; m < 2; ++m)
#pragma unroll
      for (int j = 0; j < 4; ++j) rl[m][j] = 1.0f / lacc[m][j];
#pragma unroll
    for (int m = 0; m < 2; ++m)
#pragma unroll
      for (int dn = 0; dn < 8; ++dn)
#pragma unroll
        for (int j = 0; j < 4; ++j) {
          const int row = qt * 128 + w * 32 + m * 16 + lg * 4 + j;
          ctx[(size_t)(b * 2048 + row) * 2048 + h * 128 + dn * 16 + lr] =
              __float2bfloat16(oacc[m][dn][j] * rl[m][j]);
        }
  } else {
    // disjoint plain-store partials (each element written exactly once)
    float* Op = (u < 8) ? O0 : O1;
    float* lp = (u < 8) ? l0 : l1;
    float* obase =
        Op + (((size_t)(b * 16 + h)) * 1024 + (qt * 128 - 1024 + w * 32)) * 128;
#pragma unroll
    for (int m = 0; m < 2; ++m)
#pragma unroll
      for (int dn = 0; dn < 8; ++dn)
#pragma unroll
        for (int j = 0; j < 4; ++j)
          obase[(m * 16 + lg * 4 + j) * 128 + dn * 16 + lr] = oacc[m][dn][j];
    if (lr == 0) {
      float* lbase =
          lp + ((size_t)(b * 16 + h)) * 1024 + (qt * 128 - 1024 + w * 32);
#pragma unroll
      for (int m = 0; m < 2; ++m)
#pragma unroll
        for (int j = 0; j < 4; ++j) lbase[m * 16 + lg * 4 + j] = lacc[m][j];
    }
  }
}

// ----------------------- combine split rows: ctx = (O0+O1)/(l0+l1), s>=1024
__global__ __launch_bounds__(256) void k_comb(const float* __restrict__ O0,
                                              const float* __restrict__ O1,
                                              const float* __restrict__ l0,
                                              const float* __restrict__ l1,
                                              bf16* __restrict__ ctx) {
  const int idx = blockIdx.x * 256 + threadIdx.x;  // 524288 threads x 8 floats
  const size_t base = (size_t)idx * 8;
  const size_t rowi = base >> 7;  // (b*16+h)*1024 + (s-1024)
  const float rl = 1.0f / (l0[rowi] + l1[rowi]);
  const float4 a0 = *(const float4*)&O0[base];
  const float4 b0 = *(const float4*)&O0[base + 4];
  const float4 a1 = *(const float4*)&O1[base];
  const float4 b1 = *(const float4*)&O1[base + 4];
  const int d = (int)(base & 127);
  const int s = (int)(rowi & 1023);
  const int bh = (int)(rowi >> 10);
  const int b = bh >> 4, h = bh & 15;
  bf16 o[8] = {__float2bfloat16((a0.x + a1.x) * rl), __float2bfloat16((a0.y + a1.y) * rl),
               __float2bfloat16((a0.z + a1.z) * rl), __float2bfloat16((a0.w + a1.w) * rl),
               __float2bfloat16((b0.x + b1.x) * rl), __float2bfloat16((b0.y + b1.y) * rl),
               __float2bfloat16((b0.z + b1.z) * rl), __float2bfloat16((b0.w + b1.w) * rl)};
  bf16* p = ctx + (size_t)(b * 2048 + 1024 + s) * 2048 + h * 128 + d;
  *(ushort4*)p = *(ushort4*)o;
  *(ushort4*)(p + 4) = *(ushort4*)(o + 4);
}

// ------------------------------------------------------------------- launcher
extern "C" void kernel_launch(void* const* d_in, const int* in_sizes, int n_in,
                              void* d_out, int out_size, void* d_ws, size_t ws_size,
                              hipStream_t stream) {
  const float* x = (const float*)d_in[0];
  const float* Wqkv = (const float*)d_in[1];
  const float* bqkv = (const float*)d_in[2];
  const float* Wout = (const float*)d_in[3];
  const float* bout = (const float*)d_in[4];
  float* out = (float*)d_out;

  char* ws = (char*)d_ws;
  bf16* xb    = (bf16*)(ws + 0);          // 16 MiB (dead after QKV GEMM)
  bf16* wqkvT = (bf16*)(ws + 16777216);   // 24 MiB (dead after QKV GEMM)
  bf16* woutT = (bf16*)(ws + 41943040);   // 8 MiB
  bf16* qkvb  = (bf16*)(ws + 50331648);   // 48 MiB
  bf16* vTb   = (bf16*)(ws + 100663296);  // 16 MiB
  bf16* ctxb  = (bf16*)(ws + 117440512);  // 16 MiB
  float* cosT = (float*)(ws + 134217728); // 512 KiB
  float* sinT = (float*)(ws + 134742016); // 512 KiB
  // split-KV partials overlap the dead xb/wqkvT regions:
  float* O0 = (float*)(ws + 0);               // 16 MiB
  float* O1 = (float*)(ws + 16777216);        // 16 MiB
  float* l0 = (float*)(ws + 33554432);        // 128 KiB
  float* l1 = (float*)(ws + 33685504);        // 128 KiB

  k_ropetab<<<512, 256, 0, stream>>>(cosT, sinT);
  k_cast<<<8192, 256, 0, stream>>>(x, xb, 2097152);
  k_tcast<<<dim3(192, 64), dim3(32, 8), 0, stream>>>(Wqkv, wqkvT, 2048, 6144);
  k_tcast<<<dim3(64, 64), dim3(32, 8), 0, stream>>>(Wout, woutT, 2048, 2048);
  // QKV = x @ Wqkv + b, with fused RoPE epilogue (q pre-scaled by SL2E)
  k_gemm_bt<<<dim3(48, 32), 256, 0, stream>>>(xb, wqkvT, bqkv, qkvb, 4096, 6144,
                                              2048, 1, 1, cosT, sinT);
  k_vtrans<<<dim3(64, 4, 32), dim3(32, 8), 0, stream>>>(qkvb, vTb);
  // split-KV flash attention: 768 blocks, 48KB LDS -> 3 blocks/CU
  k_attn2<<<768, 256, 0, stream>>>(qkvb, vTb, ctxb, O0, O1, l0, l1);
  k_comb<<<2048, 256, 0, stream>>>(O0, O1, l0, l1, ctxb);
  // out = ctx @ Wout + bout (fp32 out)
  k_gemm_bt<<<dim3(16, 32), 256, 0, stream>>>(ctxb, woutT, bout, out, 4096, 2048,
                                              2048, 0, 0, cosT, sinT);
}